// Round 2
// baseline (222.989 us; speedup 1.0000x reference)
//
#include <hip/hip_runtime.h>
#include <cstdint>

// HypHawkes: attn = project(expmap0(softmax((project(expmap0(q))@W.T) @ project(expmap0(ctx)).T / d)))
// Pipeline: prep (rownorm q, rownorm ctx, cvt W -> bf16) -> gemm_bt<TN=64> (qw) ->
//           gemm_bt<TN=128> (fp32 scores into d_out) -> in-place softmax+expmap+project.
// LDS layout: identity chunk mapping (chunk = 16 rows x 32 cols, lane l <-> (row=l&15,
// colchunk=l>>4)) so MFMA fragment reads are sequential 1KB wave reads — zero bank conflicts.

typedef unsigned short ushort_t;
typedef __bf16 bf16x8 __attribute__((ext_vector_type(8)));
typedef float f32x4 __attribute__((ext_vector_type(4)));

__device__ __forceinline__ unsigned short f32_to_bf16(float f) {
  unsigned int u = __float_as_uint(f);
  u = (u + 0x7fffu + ((u >> 16) & 1u)) >> 16;  // RNE; inputs are finite
  return (unsigned short)u;
}

__device__ __forceinline__ void async_copy16(const void* g, void* s) {
  __builtin_amdgcn_global_load_lds(
      (const __attribute__((address_space(1))) void*)g,
      (__attribute__((address_space(3))) void*)s, 16, 0, 0);
}

// ---------------- fused prep: rownorm+expmap+project for q/ctx, cvt for W ---
// blocks [0,n): q rows; [n,n+m): ctx rows; [n+m, n+m+1024): W cvt (1024 floats each)
__global__ void prep(const float* __restrict__ q, const float* __restrict__ ctx,
                     const float* __restrict__ W, ushort_t* __restrict__ qn,
                     ushort_t* __restrict__ cn, ushort_t* __restrict__ Wb,
                     const float* __restrict__ cptr, int n, int m) {
  const int b = blockIdx.x;
  const int tid = threadIdx.x;

  if (b >= n + m) {  // W conversion chunk
    int i = (b - n - m) * 256 + tid;
    float4 v = reinterpret_cast<const float4*>(W)[i];
    reinterpret_cast<ushort4*>(Wb)[i] =
        make_ushort4(f32_to_bf16(v.x), f32_to_bf16(v.y), f32_to_bf16(v.z), f32_to_bf16(v.w));
    return;
  }

  const int lane = tid & 63, w = tid >> 6;
  __shared__ float red[4];
  const float* x = (b < n) ? q + (size_t)b * 1024 : ctx + (size_t)(b - n) * 1024;
  ushort_t* out = (b < n) ? qn + (size_t)b * 1024 : cn + (size_t)(b - n) * 1024;

  float4 v = reinterpret_cast<const float4*>(x)[tid];
  float ss = v.x * v.x + v.y * v.y + v.z * v.z + v.w * v.w;
#pragma unroll
  for (int o = 32; o; o >>= 1) ss += __shfl_down(ss, o, 64);
  if (lane == 0) red[w] = ss;
  __syncthreads();
  ss = red[0] + red[1] + red[2] + red[3];

  const float c = *cptr;
  const float sqrtc = sqrtf(c);
  const float norm = fmaxf(sqrtf(ss), 1e-5f);            // expmap0 u_norm clamp
  const float t = tanhf(sqrtc * norm) / (sqrtc * norm);  // expmap scale
  const float en = fmaxf(t * norm, 1e-5f);               // |expmap0(u)| (project clamp)
  const float maxn = (1.0f - 4e-3f) / sqrtc;
  const float s = t * (en > maxn ? maxn / en : 1.0f);

  reinterpret_cast<ushort4*>(out)[tid] =
      make_ushort4(f32_to_bf16(v.x * s), f32_to_bf16(v.y * s),
                   f32_to_bf16(v.z * s), f32_to_bf16(v.w * s));
}

// ---------------- C = A (Mx K) * B^T (B is NxK row-major), bf16 in ----------
// TM=128 fixed. TN=128: 4 waves 2x2, each 64x64 (acc 4x4). TN=64: 4 waves 4x1,
// each 32x64 (acc 2x4), grid.y doubles -> 2 blocks/CU for small-N GEMMs.
// Chunk = 16 rows x 32 K-cols (1KB), identity lane mapping (conflict-free reads).
template <int TN, bool BF16_OUT>
__global__ __launch_bounds__(256) void gemm_bt(const ushort_t* __restrict__ A,
                                               const ushort_t* __restrict__ B,
                                               ushort_t* __restrict__ Cb,
                                               float* __restrict__ Cf, int K, int N) {
  constexpr int ACH = 8;        // A chunks (128 rows / 16)
  constexpr int BCH = TN / 16;  // B chunks
  constexpr int CT = ACH + BCH;
  constexpr int CPW = CT / 4;                    // chunks staged per wave
  constexpr int RT = (TN == 128) ? 4 : 2;        // 16-row tiles per wave

  __shared__ __align__(16) ushort_t sm[CT * 512];
  ushort_t* As = sm;
  ushort_t* Bs = sm + ACH * 512;

  const int tid = threadIdx.x;
  const int w = tid >> 6;
  const int lane = tid & 63;
  const int lane15 = lane & 15;
  const int quad = lane >> 4;

  int wr, wc;
  if (TN == 128) { wr = w >> 1; wc = w & 1; }
  else { wr = w; wc = 0; }

  const size_t rowBase = (size_t)blockIdx.x * 128;
  const size_t colBase = (size_t)blockIdx.y * TN;

  // staging sources: wave w fills chunks [w*CPW, (w+1)*CPW)
  const ushort_t* gsrc[CPW];
  ushort_t* gdst[CPW];
#pragma unroll
  for (int cc = 0; cc < CPW; ++cc) {
    int c = w * CPW + cc;
    if (c < ACH)
      gsrc[cc] = A + (rowBase + (size_t)(c * 16 + lane15)) * K + quad * 8;
    else
      gsrc[cc] = B + (colBase + (size_t)((c - ACH) * 16 + lane15)) * K + quad * 8;
    gdst[cc] = sm + c * 512;  // HW adds lane*16B
  }

  f32x4 acc[RT][4];
#pragma unroll
  for (int i = 0; i < RT; ++i)
#pragma unroll
    for (int j = 0; j < 4; ++j) acc[i][j] = f32x4{0.f, 0.f, 0.f, 0.f};

  for (int k0 = 0; k0 < K; k0 += 32) {
#pragma unroll
    for (int cc = 0; cc < CPW; ++cc) async_copy16(gsrc[cc] + k0, gdst[cc]);
    __syncthreads();

    bf16x8 af[RT], bv[4];
#pragma unroll
    for (int i = 0; i < RT; ++i)
      af[i] = *reinterpret_cast<const bf16x8*>(&As[(wr * RT + i) * 512 + lane * 8]);
#pragma unroll
    for (int j = 0; j < 4; ++j)
      bv[j] = *reinterpret_cast<const bf16x8*>(&Bs[(wc * 4 + j) * 512 + lane * 8]);
#pragma unroll
    for (int i = 0; i < RT; ++i)
#pragma unroll
      for (int j = 0; j < 4; ++j)
        acc[i][j] = __builtin_amdgcn_mfma_f32_16x16x32_bf16(af[i], bv[j], acc[i][j], 0, 0, 0);
    __syncthreads();
  }

  // C/D layout: col = lane&15, row = quad*4 + reg
#pragma unroll
  for (int i = 0; i < RT; ++i)
#pragma unroll
    for (int j = 0; j < 4; ++j)
#pragma unroll
      for (int r = 0; r < 4; ++r) {
        size_t row = rowBase + (size_t)(wr * (RT * 16) + i * 16 + quad * 4 + r);
        size_t col = colBase + (size_t)(wc * 64 + j * 16 + lane15);
        float val = acc[i][j][r];
        if (BF16_OUT)
          Cb[row * N + col] = f32_to_bf16(val);
        else
          Cf[row * N + col] = val;
      }
}

// ---------------- in-place softmax(row/d) + expmap0 + project --------------
__global__ void softmax_expmap(float* __restrict__ S,
                               const float* __restrict__ cptr, float invd) {
  const int tid = threadIdx.x;
  const int lane = tid & 63, w = tid >> 6;
  __shared__ float red[4];
  float* rp = S + (size_t)blockIdx.x * 4096;

  float4 v[4];
#pragma unroll
  for (int i = 0; i < 4; ++i) v[i] = reinterpret_cast<float4*>(rp)[i * 256 + tid];

  float mx = -1e30f;
#pragma unroll
  for (int i = 0; i < 4; ++i) {
    v[i].x *= invd; v[i].y *= invd; v[i].z *= invd; v[i].w *= invd;
    mx = fmaxf(mx, fmaxf(fmaxf(v[i].x, v[i].y), fmaxf(v[i].z, v[i].w)));
  }
#pragma unroll
  for (int o = 32; o; o >>= 1) mx = fmaxf(mx, __shfl_down(mx, o, 64));
  if (lane == 0) red[w] = mx;
  __syncthreads();
  mx = fmaxf(fmaxf(red[0], red[1]), fmaxf(red[2], red[3]));
  __syncthreads();

  float sum = 0.f, sq = 0.f;
#pragma unroll
  for (int i = 0; i < 4; ++i) {
    v[i].x = expf(v[i].x - mx); v[i].y = expf(v[i].y - mx);
    v[i].z = expf(v[i].z - mx); v[i].w = expf(v[i].w - mx);
    sum += v[i].x + v[i].y + v[i].z + v[i].w;
    sq += v[i].x * v[i].x + v[i].y * v[i].y + v[i].z * v[i].z + v[i].w * v[i].w;
  }
#pragma unroll
  for (int o = 32; o; o >>= 1) sum += __shfl_down(sum, o, 64);
  if (lane == 0) red[w] = sum;
  __syncthreads();
  sum = red[0] + red[1] + red[2] + red[3];
  __syncthreads();
#pragma unroll
  for (int o = 32; o; o >>= 1) sq += __shfl_down(sq, o, 64);
  if (lane == 0) red[w] = sq;
  __syncthreads();
  sq = red[0] + red[1] + red[2] + red[3];

  const float c = *cptr;
  const float sqrtc = sqrtf(c);
  const float anorm = sqrtf(sq) / sum;       // |attn|
  const float an = fmaxf(anorm, 1e-5f);      // expmap0 clamp
  const float t = tanhf(sqrtc * an) / (sqrtc * an);
  const float pn = fmaxf(t * anorm, 1e-5f);  // |expmap0(attn)| (project clamp)
  const float maxn = (1.0f - 4e-3f) / sqrtc;
  const float g = t * (pn > maxn ? maxn / pn : 1.0f) / sum;

#pragma unroll
  for (int i = 0; i < 4; ++i) {
    v[i].x *= g; v[i].y *= g; v[i].z *= g; v[i].w *= g;
    reinterpret_cast<float4*>(rp)[i * 256 + tid] = v[i];
  }
}

extern "C" void kernel_launch(void* const* d_in, const int* in_sizes, int n_in,
                              void* d_out, int out_size, void* d_ws, size_t ws_size,
                              hipStream_t stream) {
  const float* query = (const float*)d_in[0];
  const float* context = (const float*)d_in[1];
  const float* W = (const float*)d_in[2];
  const float* cptr = (const float*)d_in[3];

  const int d = 1024;
  const int n = in_sizes[0] / d;  // 4096
  const int m = in_sizes[1] / d;  // 4096

  ushort_t* qn = (ushort_t*)d_ws;     // n*d bf16
  ushort_t* cn = qn + (size_t)n * d;  // m*d bf16
  ushort_t* Wb = cn + (size_t)m * d;  // d*d bf16
  ushort_t* qw = Wb + (size_t)d * d;  // n*d bf16
  float* scores = (float*)d_out;      // n*m fp32, softmaxed in place

  prep<<<n + m + d * d / 1024, 256, 0, stream>>>(query, context, W, qn, cn, Wb, cptr, n, m);
  // qw = qn @ Wb^T : M=n, N=d, TN=64 -> grid (32,16)=512 blocks
  gemm_bt<64, true><<<dim3(n / 128, d / 64), 256, 0, stream>>>(qn, Wb, qw, nullptr, d, d);
  // scores = qw @ cn^T : M=n, N=m, TN=128 -> grid (32,32)=1024 blocks
  gemm_bt<128, false><<<dim3(n / 128, m / 128), 256, 0, stream>>>(qw, cn, nullptr, scores, d, m);
  softmax_expmap<<<n, 256, 0, stream>>>(scores, cptr, 1.0f / (float)d);
}

// Round 3
// 195.209 us; speedup vs baseline: 1.1423x; 1.1423x over previous
//
#include <hip/hip_runtime.h>
#include <cstdint>

// HypHawkes: attn = project(expmap0(softmax((project(expmap0(q))@W.T) @ project(expmap0(ctx)).T / d)))
//
// All bf16 GEMM operands (qn, cn, Wb, qw) live in MFMA-fragment-tiled layout:
//   chunk (rt, kt) = 1KB at ((rt*(K/32) + kt) * 512) elements; slot l in [0,64)
//   holds X[rt*16 + (l&15)][kt*32 + (l>>4)*8 .. +8].
// So gemm staging is a contiguous 1KB global_load_lds per wave (8 full cachelines),
// the LDS image is identical to the global image, and MFMA fragment reads are
// sequential lane*16B ds_read_b128 — zero bank conflicts AND perfect coalescing.

typedef unsigned short ushort_t;
typedef __bf16 bf16x8 __attribute__((ext_vector_type(8)));
typedef float f32x4 __attribute__((ext_vector_type(4)));

__device__ __forceinline__ unsigned short f32_to_bf16(float f) {
  unsigned int u = __float_as_uint(f);
  u = (u + 0x7fffu + ((u >> 16) & 1u)) >> 16;  // RNE; inputs are finite
  return (unsigned short)u;
}

__device__ __forceinline__ void async_copy16(const void* g, void* s) {
  __builtin_amdgcn_global_load_lds(
      (const __attribute__((address_space(1))) void*)g,
      (__attribute__((address_space(3))) void*)s, 16, 0, 0);
}

// ---------------- prep: one block per 16-row tile, K=1024 fixed -------------
// blocks [0,nt): q tiles -> qn; [nt,nt+mt): ctx -> cn; [nt+mt, +64): W -> Wb.
// Phase 1: 16 coalesced 4KB row loads (+ row-norm reduction for q/ctx).
// Phase 2: scale rows, write bf16 in tiled layout.
__global__ void prep(const float* __restrict__ q, const float* __restrict__ ctx,
                     const float* __restrict__ W, ushort_t* __restrict__ qn,
                     ushort_t* __restrict__ cn, ushort_t* __restrict__ Wb,
                     const float* __restrict__ cptr, int nt, int mt) {
  const int b = blockIdx.x;
  const int tid = threadIdx.x;
  const int lane = tid & 63, w = tid >> 6;

  const float* src;
  ushort_t* dst;
  bool norm = true;
  int rt;
  if (b < nt) { src = q; dst = qn; rt = b; }
  else if (b < nt + mt) { src = ctx; dst = cn; rt = b - nt; }
  else { src = W; dst = Wb; rt = b - nt - mt; norm = false; }

  __shared__ float red[16][4];
  __shared__ float scale[16];
  const float* xt = src + (size_t)rt * 16 * 1024;

  float4 v[16];
#pragma unroll
  for (int k = 0; k < 16; ++k) {
    v[k] = reinterpret_cast<const float4*>(xt + k * 1024)[tid];
    if (norm) {
      float ss = v[k].x * v[k].x + v[k].y * v[k].y + v[k].z * v[k].z + v[k].w * v[k].w;
#pragma unroll
      for (int o = 32; o; o >>= 1) ss += __shfl_down(ss, o, 64);
      if (lane == 0) red[k][w] = ss;
    }
  }
  if (norm) {
    __syncthreads();
    if (tid < 16) {
      float ss = red[tid][0] + red[tid][1] + red[tid][2] + red[tid][3];
      const float c = *cptr;
      const float sqrtc = sqrtf(c);
      const float nrm = fmaxf(sqrtf(ss), 1e-5f);             // expmap0 clamp
      const float t = tanhf(sqrtc * nrm) / (sqrtc * nrm);    // expmap scale
      const float en = fmaxf(t * nrm, 1e-5f);                // project clamp
      const float maxn = (1.0f - 4e-3f) / sqrtc;
      scale[tid] = t * (en > maxn ? maxn / en : 1.0f);
    }
    __syncthreads();
  }

  // tiled write: col = tid*4; kt = tid>>3; quad = (tid>>1)&3; slot = k + quad*16
  const int col = tid * 4;
  const size_t base = ((size_t)rt * 32 + (col >> 5)) * 512 + (((col >> 3) & 3) << 4) * 8 + (col & 7);
#pragma unroll
  for (int k = 0; k < 16; ++k) {
    float s = norm ? scale[k] : 1.0f;
    ushort4 o = make_ushort4(f32_to_bf16(v[k].x * s), f32_to_bf16(v[k].y * s),
                             f32_to_bf16(v[k].z * s), f32_to_bf16(v[k].w * s));
    *reinterpret_cast<ushort4*>(dst + base + (size_t)k * 8) = o;
  }
}

// ---------------- C = A (MxK) * B^T (B is NxK), both in tiled layout --------
// TM=128. TN=128: 4 waves 2x2 (acc 4x4). TN=64: 4 waves 4x1 (acc 2x4).
// Staging: wave-contiguous 1KB chunks; chunk c advances 1KB per K-step.
template <int TN, bool BF16_OUT>
__global__ __launch_bounds__(256) void gemm_bt(const ushort_t* __restrict__ A,
                                               const ushort_t* __restrict__ B,
                                               ushort_t* __restrict__ Cb,
                                               float* __restrict__ Cf, int K, int N) {
  constexpr int ACH = 8;        // A chunks (128 rows / 16)
  constexpr int BCH = TN / 16;  // B chunks
  constexpr int CT = ACH + BCH;
  constexpr int CPW = CT / 4;              // chunks staged per wave
  constexpr int RT = (TN == 128) ? 4 : 2;  // 16-row tiles per wave

  __shared__ __align__(16) ushort_t sm[CT * 512];

  const int tid = threadIdx.x;
  const int w = tid >> 6;
  const int lane = tid & 63;
  const int lane15 = lane & 15;
  const int quad = lane >> 4;
  const int KT = K >> 5;  // number of 32-wide K tiles

  int wr, wc;
  if (TN == 128) { wr = w >> 1; wc = w & 1; }
  else { wr = w; wc = 0; }

  // staging sources: wave w fills chunks [w*CPW, (w+1)*CPW)
  const ushort_t* gsrc[CPW];
  ushort_t* gdst[CPW];
#pragma unroll
  for (int cc = 0; cc < CPW; ++cc) {
    int c = w * CPW + cc;
    if (c < ACH)
      gsrc[cc] = A + ((size_t)(blockIdx.x * ACH + c) * KT) * 512 + lane * 8;
    else
      gsrc[cc] = B + ((size_t)(blockIdx.y * BCH + (c - ACH)) * KT) * 512 + lane * 8;
    gdst[cc] = sm + c * 512;  // HW adds lane*16B
  }

  f32x4 acc[RT][4];
#pragma unroll
  for (int i = 0; i < RT; ++i)
#pragma unroll
    for (int j = 0; j < 4; ++j) acc[i][j] = f32x4{0.f, 0.f, 0.f, 0.f};

  for (int kt = 0; kt < KT; ++kt) {
#pragma unroll
    for (int cc = 0; cc < CPW; ++cc) async_copy16(gsrc[cc] + (size_t)kt * 512, gdst[cc]);
    __syncthreads();

    bf16x8 af[RT], bv[4];
#pragma unroll
    for (int i = 0; i < RT; ++i)
      af[i] = *reinterpret_cast<const bf16x8*>(&sm[(wr * RT + i) * 512 + lane * 8]);
#pragma unroll
    for (int j = 0; j < 4; ++j)
      bv[j] = *reinterpret_cast<const bf16x8*>(&sm[(ACH + wc * 4 + j) * 512 + lane * 8]);
#pragma unroll
    for (int i = 0; i < RT; ++i)
#pragma unroll
      for (int j = 0; j < 4; ++j)
        acc[i][j] = __builtin_amdgcn_mfma_f32_16x16x32_bf16(af[i], bv[j], acc[i][j], 0, 0, 0);
    __syncthreads();
  }

  // C/D layout: col = lane&15, row = quad*4 + reg
#pragma unroll
  for (int i = 0; i < RT; ++i)
#pragma unroll
    for (int j = 0; j < 4; ++j)
#pragma unroll
      for (int r = 0; r < 4; ++r) {
        int row = blockIdx.x * 128 + wr * (RT * 16) + i * 16 + quad * 4 + r;
        int col = blockIdx.y * TN + wc * 64 + j * 16 + lane15;
        float val = acc[i][j][r];
        if (BF16_OUT) {
          // write in tiled layout (this is gemm2's A operand)
          size_t off = ((size_t)(row >> 4) * (N >> 5) + (col >> 5)) * 512 +
                       (size_t)(((row & 15) + (((col >> 3) & 3) << 4)) * 8) + (col & 7);
          Cb[off] = f32_to_bf16(val);
        } else {
          Cf[(size_t)row * N + col] = val;
        }
      }
}

// ---------------- in-place softmax(row/d) + expmap0 + project --------------
__global__ void softmax_expmap(float* __restrict__ S,
                               const float* __restrict__ cptr, float invd) {
  const int tid = threadIdx.x;
  const int lane = tid & 63, w = tid >> 6;
  __shared__ float red[4];
  float* rp = S + (size_t)blockIdx.x * 4096;

  float4 v[4];
#pragma unroll
  for (int i = 0; i < 4; ++i) v[i] = reinterpret_cast<float4*>(rp)[i * 256 + tid];

  float mx = -1e30f;
#pragma unroll
  for (int i = 0; i < 4; ++i) {
    v[i].x *= invd; v[i].y *= invd; v[i].z *= invd; v[i].w *= invd;
    mx = fmaxf(mx, fmaxf(fmaxf(v[i].x, v[i].y), fmaxf(v[i].z, v[i].w)));
  }
#pragma unroll
  for (int o = 32; o; o >>= 1) mx = fmaxf(mx, __shfl_down(mx, o, 64));
  if (lane == 0) red[w] = mx;
  __syncthreads();
  mx = fmaxf(fmaxf(red[0], red[1]), fmaxf(red[2], red[3]));
  __syncthreads();

  float sum = 0.f, sq = 0.f;
#pragma unroll
  for (int i = 0; i < 4; ++i) {
    v[i].x = expf(v[i].x - mx); v[i].y = expf(v[i].y - mx);
    v[i].z = expf(v[i].z - mx); v[i].w = expf(v[i].w - mx);
    sum += v[i].x + v[i].y + v[i].z + v[i].w;
    sq += v[i].x * v[i].x + v[i].y * v[i].y + v[i].z * v[i].z + v[i].w * v[i].w;
  }
#pragma unroll
  for (int o = 32; o; o >>= 1) sum += __shfl_down(sum, o, 64);
  if (lane == 0) red[w] = sum;
  __syncthreads();
  sum = red[0] + red[1] + red[2] + red[3];
  __syncthreads();
#pragma unroll
  for (int o = 32; o; o >>= 1) sq += __shfl_down(sq, o, 64);
  if (lane == 0) red[w] = sq;
  __syncthreads();
  sq = red[0] + red[1] + red[2] + red[3];

  const float c = *cptr;
  const float sqrtc = sqrtf(c);
  const float anorm = sqrtf(sq) / sum;       // |attn|
  const float an = fmaxf(anorm, 1e-5f);      // expmap0 clamp
  const float t = tanhf(sqrtc * an) / (sqrtc * an);
  const float pn = fmaxf(t * anorm, 1e-5f);  // |expmap0(attn)| (project clamp)
  const float maxn = (1.0f - 4e-3f) / sqrtc;
  const float g = t * (pn > maxn ? maxn / pn : 1.0f) / sum;

#pragma unroll
  for (int i = 0; i < 4; ++i) {
    v[i].x *= g; v[i].y *= g; v[i].z *= g; v[i].w *= g;
    reinterpret_cast<float4*>(rp)[i * 256 + tid] = v[i];
  }
}

extern "C" void kernel_launch(void* const* d_in, const int* in_sizes, int n_in,
                              void* d_out, int out_size, void* d_ws, size_t ws_size,
                              hipStream_t stream) {
  const float* query = (const float*)d_in[0];
  const float* context = (const float*)d_in[1];
  const float* W = (const float*)d_in[2];
  const float* cptr = (const float*)d_in[3];

  const int d = 1024;
  const int n = in_sizes[0] / d;  // 4096
  const int m = in_sizes[1] / d;  // 4096
  const int nt = n / 16, mt = m / 16, wt = d / 16;

  ushort_t* qn = (ushort_t*)d_ws;     // n*d bf16, tiled
  ushort_t* cn = qn + (size_t)n * d;  // m*d bf16, tiled
  ushort_t* Wb = cn + (size_t)m * d;  // d*d bf16, tiled
  ushort_t* qw = Wb + (size_t)d * d;  // n*d bf16, tiled
  float* scores = (float*)d_out;      // n*m fp32, softmaxed in place

  prep<<<nt + mt + wt, 256, 0, stream>>>(query, context, W, qn, cn, Wb, cptr, nt, mt);
  // qw = qn @ Wb^T : M=n, N=d, TN=64 -> grid (32,16)=512 blocks
  gemm_bt<64, true><<<dim3(n / 128, d / 64), 256, 0, stream>>>(qn, Wb, qw, nullptr, d, d);
  // scores = qw @ cn^T : M=n, N=m, TN=128 -> grid (32,32)=1024 blocks
  gemm_bt<128, false><<<dim3(n / 128, m / 128), 256, 0, stream>>>(qw, cn, nullptr, scores, d, m);
  softmax_expmap<<<n, 256, 0, stream>>>(scores, cptr, 1.0f / (float)d);
}

// Round 5
// 177.948 us; speedup vs baseline: 1.2531x; 1.0970x over previous
//
#include <hip/hip_runtime.h>
#include <cstdint>

// HypHawkes: attn = project(expmap0(softmax((project(expmap0(q))@W.T) @ project(expmap0(ctx)).T / d)))
// R5 (= R4 fixed): round-1 row-major staging layout (empirically fastest; its LDS
// conflicts are hidden under staging latency), BK=64 via two 32-col LDS planes
// (halves barriers), TM templated (gemm1 = 64x128 -> 512 blocks), distinct kernel
// names per stage, softmax without max pass (logits ~ +/-2e-3; overflow impossible).

typedef unsigned short ushort_t;
typedef __bf16 bf16x8 __attribute__((ext_vector_type(8)));
typedef float f32x4 __attribute__((ext_vector_type(4)));

__device__ __forceinline__ unsigned short f32_to_bf16(float f) {
  unsigned int u = __float_as_uint(f);
  u = (u + 0x7fffu + ((u >> 16) & 1u)) >> 16;  // RNE; inputs are finite
  return (unsigned short)u;
}

__device__ __forceinline__ void async_copy16(const void* g, void* s) {
  __builtin_amdgcn_global_load_lds(
      (const __attribute__((address_space(1))) void*)g,
      (__attribute__((address_space(3))) void*)s, 16, 0, 0);
}

// ---------------- fused prep: rownorm+expmap+project for q/ctx, cvt for W ---
// blocks [0,n): q rows; [n,n+m): ctx rows; [n+m, ...): W cvt (1024 floats each)
__global__ void prep_rows(const float* __restrict__ q, const float* __restrict__ ctx,
                          const float* __restrict__ W, ushort_t* __restrict__ qn,
                          ushort_t* __restrict__ cn, ushort_t* __restrict__ Wb,
                          const float* __restrict__ cptr, int n, int m) {
  const int b = blockIdx.x;
  const int tid = threadIdx.x;

  if (b >= n + m) {  // W conversion chunk
    int i = (b - n - m) * 256 + tid;
    float4 v = reinterpret_cast<const float4*>(W)[i];
    reinterpret_cast<ushort4*>(Wb)[i] =
        make_ushort4(f32_to_bf16(v.x), f32_to_bf16(v.y), f32_to_bf16(v.z), f32_to_bf16(v.w));
    return;
  }

  const int lane = tid & 63, w = tid >> 6;
  __shared__ float red[4];
  const float* x = (b < n) ? q + (size_t)b * 1024 : ctx + (size_t)(b - n) * 1024;
  ushort_t* out = (b < n) ? qn + (size_t)b * 1024 : cn + (size_t)(b - n) * 1024;

  float4 v = reinterpret_cast<const float4*>(x)[tid];
  float ss = v.x * v.x + v.y * v.y + v.z * v.z + v.w * v.w;
#pragma unroll
  for (int o = 32; o; o >>= 1) ss += __shfl_down(ss, o, 64);
  if (lane == 0) red[w] = ss;
  __syncthreads();
  ss = red[0] + red[1] + red[2] + red[3];

  const float c = *cptr;
  const float sqrtc = sqrtf(c);
  const float norm = fmaxf(sqrtf(ss), 1e-5f);            // expmap0 u_norm clamp
  const float t = tanhf(sqrtc * norm) / (sqrtc * norm);  // expmap scale
  const float en = fmaxf(t * norm, 1e-5f);               // |expmap0(u)| (project clamp)
  const float maxn = (1.0f - 4e-3f) / sqrtc;
  const float s = t * (en > maxn ? maxn / en : 1.0f);

  reinterpret_cast<ushort4*>(out)[tid] =
      make_ushort4(f32_to_bf16(v.x * s), f32_to_bf16(v.y * s),
                   f32_to_bf16(v.z * s), f32_to_bf16(v.w * s));
}

// ---------------- C = A (MxK) * B^T (B is NxK row-major), bf16, row-major ---
// TN=128 fixed, BK=64 as two 32-col planes. 4 waves 2x2; wave tile (TM/2)x64.
// Plane layout (round-1): X[h][row][32cols] row-major; chunk = 16 rows x 32 cols
// = 1KB, staged by one global_load_lds (lane -> (row=lane>>2, col8=(lane&3)*8)).
template <int TM, bool BF16_OUT>
__device__ __forceinline__ void gemm_core(const ushort_t* __restrict__ A,
                                          const ushort_t* __restrict__ B,
                                          ushort_t* __restrict__ Cb,
                                          float* __restrict__ Cf, int K, int N) {
  constexpr int ACH = TM / 16;    // A chunks per plane
  constexpr int BCH = 8;          // B chunks per plane
  constexpr int CPP = ACH + BCH;  // chunks per plane
  constexpr int CPW = CPP / 2;    // chunks per wave (2 planes over 4 waves)
  constexpr int RT = TM / 32;     // 16-row tiles per wave

  __shared__ __align__(16) ushort_t sm[2 * CPP * 512];

  const int tid = threadIdx.x;
  const int w = tid >> 6;
  const int lane = tid & 63;
  const int lane15 = lane & 15;
  const int quad = lane >> 4;
  const int wr = w >> 1, wc = w & 1;

  const int rowBase = blockIdx.x * TM;
  const int colBase = blockIdx.y * 128;

  const int srow = lane >> 2;        // 0..15
  const int scolE = (lane & 3) * 8;  // 0,8,16,24

  const ushort_t* gsrc[CPW];
  ushort_t* gdst[CPW];
#pragma unroll
  for (int i = 0; i < CPW; ++i) {
    int g = w * CPW + i;
    int h = g / CPP, c = g % CPP;
    if (c < ACH)
      gsrc[i] = A + (size_t)(rowBase + c * 16 + srow) * K + h * 32 + scolE;
    else
      gsrc[i] = B + (size_t)(colBase + (c - ACH) * 16 + srow) * K + h * 32 + scolE;
    gdst[i] = sm + (h * CPP + c) * 512;  // wave-uniform; HW adds lane*16B
  }

  f32x4 acc[RT][4];
#pragma unroll
  for (int i = 0; i < RT; ++i)
#pragma unroll
    for (int j = 0; j < 4; ++j) acc[i][j] = f32x4{0.f, 0.f, 0.f, 0.f};

  for (int k0 = 0; k0 < K; k0 += 64) {
#pragma unroll
    for (int i = 0; i < CPW; ++i) async_copy16(gsrc[i] + k0, gdst[i]);
    __syncthreads();

#pragma unroll
    for (int h = 0; h < 2; ++h) {
      bf16x8 af[RT], bv[4];
#pragma unroll
      for (int i = 0; i < RT; ++i)
        af[i] = *reinterpret_cast<const bf16x8*>(
            &sm[h * CPP * 512 + (wr * RT + i) * 512 + lane15 * 32 + quad * 8]);
#pragma unroll
      for (int j = 0; j < 4; ++j)
        bv[j] = *reinterpret_cast<const bf16x8*>(
            &sm[h * CPP * 512 + (ACH + wc * 4 + j) * 512 + lane15 * 32 + quad * 8]);
#pragma unroll
      for (int i = 0; i < RT; ++i)
#pragma unroll
        for (int j = 0; j < 4; ++j)
          acc[i][j] = __builtin_amdgcn_mfma_f32_16x16x32_bf16(af[i], bv[j], acc[i][j], 0, 0, 0);
    }
    __syncthreads();
  }

  // C/D layout: col = lane&15, row = quad*4 + reg
#pragma unroll
  for (int i = 0; i < RT; ++i)
#pragma unroll
    for (int j = 0; j < 4; ++j)
#pragma unroll
      for (int r = 0; r < 4; ++r) {
        int row = rowBase + wr * (RT * 16) + i * 16 + quad * 4 + r;
        int col = colBase + wc * 64 + j * 16 + lane15;
        float val = acc[i][j][r];
        if (BF16_OUT)
          Cb[(size_t)row * N + col] = f32_to_bf16(val);
        else
          Cf[(size_t)row * N + col] = val;
      }
}

// distinct kernel names for profiling attribution
__global__ __launch_bounds__(256) void gemm_qw(const ushort_t* __restrict__ A,
                                               const ushort_t* __restrict__ B,
                                               ushort_t* __restrict__ Cb, int K, int N) {
  gemm_core<64, true>(A, B, Cb, nullptr, K, N);
}
__global__ __launch_bounds__(256) void gemm_sc(const ushort_t* __restrict__ A,
                                               const ushort_t* __restrict__ B,
                                               float* __restrict__ Cf, int K, int N) {
  gemm_core<128, false>(A, B, nullptr, Cf, K, N);
}

// ---------------- in-place softmax(row/d) + expmap0 + project --------------
// No max pass: logits = scores/1024 are within ~+/-2e-3 (|q|,|ctx| < 1 on the ball,
// |qW| bounded by sigma_max(W)), so exp never overflows and max-sub is a no-op at tol.
__global__ void softmax_hyp(float* __restrict__ S, const float* __restrict__ cptr,
                            float invd) {
  const int tid = threadIdx.x;
  const int lane = tid & 63, w = tid >> 6;
  __shared__ float redS[4], redQ[4];
  float* rp = S + (size_t)blockIdx.x * 4096;

  float4 v[4];
#pragma unroll
  for (int i = 0; i < 4; ++i) v[i] = reinterpret_cast<float4*>(rp)[i * 256 + tid];

  float sum = 0.f, sq = 0.f;
#pragma unroll
  for (int i = 0; i < 4; ++i) {
    v[i].x = __expf(v[i].x * invd); v[i].y = __expf(v[i].y * invd);
    v[i].z = __expf(v[i].z * invd); v[i].w = __expf(v[i].w * invd);
    sum += v[i].x + v[i].y + v[i].z + v[i].w;
    sq += v[i].x * v[i].x + v[i].y * v[i].y + v[i].z * v[i].z + v[i].w * v[i].w;
  }
#pragma unroll
  for (int o = 32; o; o >>= 1) {
    sum += __shfl_down(sum, o, 64);
    sq += __shfl_down(sq, o, 64);
  }
  if (lane == 0) { redS[w] = sum; redQ[w] = sq; }
  __syncthreads();
  sum = redS[0] + redS[1] + redS[2] + redS[3];
  sq = redQ[0] + redQ[1] + redQ[2] + redQ[3];

  const float c = *cptr;
  const float sqrtc = sqrtf(c);
  const float anorm = sqrtf(sq) / sum;       // |attn|
  const float an = fmaxf(anorm, 1e-5f);      // expmap0 clamp
  const float t = tanhf(sqrtc * an) / (sqrtc * an);
  const float pn = fmaxf(t * anorm, 1e-5f);  // |expmap0(attn)| (project clamp)
  const float maxn = (1.0f - 4e-3f) / sqrtc;
  const float g = t * (pn > maxn ? maxn / pn : 1.0f) / sum;

#pragma unroll
  for (int i = 0; i < 4; ++i) {
    v[i].x *= g; v[i].y *= g; v[i].z *= g; v[i].w *= g;
    reinterpret_cast<float4*>(rp)[i * 256 + tid] = v[i];
  }
}

extern "C" void kernel_launch(void* const* d_in, const int* in_sizes, int n_in,
                              void* d_out, int out_size, void* d_ws, size_t ws_size,
                              hipStream_t stream) {
  const float* query = (const float*)d_in[0];
  const float* context = (const float*)d_in[1];
  const float* W = (const float*)d_in[2];
  const float* cptr = (const float*)d_in[3];

  const int d = 1024;
  const int n = in_sizes[0] / d;  // 4096
  const int m = in_sizes[1] / d;  // 4096

  ushort_t* qn = (ushort_t*)d_ws;     // n*d bf16, row-major
  ushort_t* cn = qn + (size_t)n * d;  // m*d
  ushort_t* Wb = cn + (size_t)m * d;  // d*d
  ushort_t* qw = Wb + (size_t)d * d;  // n*d
  float* scores = (float*)d_out;      // n*m fp32, softmaxed in place

  prep_rows<<<n + m + d * d / 1024, 256, 0, stream>>>(query, context, W, qn, cn, Wb, cptr, n, m);
  // qw = qn @ Wb^T : TM=64 -> grid (64,8)=512 blocks
  gemm_qw<<<dim3(n / 64, d / 128), 256, 0, stream>>>(qn, Wb, qw, d, d);
  // scores = qw @ cn^T : TM=128 -> grid (32,32)=1024 blocks
  gemm_sc<<<dim3(n / 128, m / 128), 256, 0, stream>>>(qw, cn, scores, d, m);
  softmax_hyp<<<n, 256, 0, stream>>>(scores, cptr, 1.0f / (float)d);
}